// Round 1
// baseline (590.346 us; speedup 1.0000x reference)
//
#include <hip/hip_runtime.h>
#include <hip/hip_bf16.h>
#include <stdint.h>
#include <stddef.h>

#define NN 8192
#define DD 128
#define PADW 136    // LDS row stride in bf16: 272 B, breaks 16-way conflicts
#define PANELS 16   // j-panel groups (partial-sum copies)
#define SUBT 4      // 128-col j-subtiles per block: PANELS*SUBT*128 == NN

typedef __attribute__((ext_vector_type(8))) short bf16x8;
typedef __attribute__((ext_vector_type(4))) float f32x4;

static __device__ __forceinline__ unsigned short f2bf(float x) {
  __hip_bfloat16 h = __float2bfloat16(x);
  return *(unsigned short*)&h;
}

// ---------------------------------------------------------------------------
// Kernel 1: row-normalize features (fp32) and cast to bf16. One wave per row.
// ---------------------------------------------------------------------------
__global__ __launch_bounds__(256) void normalize_kernel(
    const float* __restrict__ f, __hip_bfloat16* __restrict__ fn) {
  const int wave = threadIdx.x >> 6;
  const int lane = threadIdx.x & 63;
  const int row = blockIdx.x * 4 + wave;
  const float2 v = ((const float2*)(f + (size_t)row * DD))[lane];
  float ss = v.x * v.x + v.y * v.y;
#pragma unroll
  for (int m = 1; m < 64; m <<= 1) ss += __shfl_xor(ss, m, 64);
  const float inv = 1.0f / fmaxf(sqrtf(ss), 1e-8f);
  __hip_bfloat162 o;
  o.x = __float2bfloat16(v.x * inv);
  o.y = __float2bfloat16(v.y * inv);
  ((__hip_bfloat162*)(fn + (size_t)row * DD))[lane] = o;
}

// ---------------------------------------------------------------------------
// Kernel 2: per block: 4 j-subtiles of {128x128 MFMA GEMM -> exp -> LDS ->
// masked row accumulation}. Atomic-free: per-row partials accumulate in
// registers across subtiles (lane-local, reduction deferred), then one plain
// store per row into PANELS partial arrays.
//
// Mask loads are software-pipelined depth-2 through a 3-slot register buffer
// so each iteration's ~900-cycle HBM latency hides under the previous
// iteration's compute.
// ---------------------------------------------------------------------------
__global__ __launch_bounds__(256, 4) void ssnt_main(
    const __hip_bfloat16* __restrict__ fn,
    const int* __restrict__ pmask,
    const int* __restrict__ nmask,
    float* __restrict__ pP, float* __restrict__ nP, float* __restrict__ cP) {
  __shared__ __hip_bfloat16 sim[128 * PADW];  // 34 KB -> 4 blocks/CU

  const int tid = threadIdx.x;
  const int lane = tid & 63;
  const int quad = lane >> 4;
  const int l16 = lane & 15;
  const int wx = (tid >> 6) & 1;
  const int wy = tid >> 7;
  const int rGrp = tid >> 4;  // 16 rows per phase-3 iteration
  const int cl = tid & 15;    // 16 col-groups x 8 cols = 128 cols

  const int I0g = blockIdx.y * 128;
  const int I0 = I0g + wy * 64;

  // per-row partial accumulators, lane-local (reduced once in the epilogue)
  float accP[8] = {}, accN[8] = {}, accC[8] = {};

#pragma unroll 1
  for (int js = 0; js < SUBT; ++js) {
    const int J0g = (blockIdx.x * SUBT + js) * 128;
    const int J0 = J0g + wx * 64;

    // ---- Phase 1: GEMM (fragments straight from L2; fn is 2 MB) ----
    f32x4 acc[4][4] = {};
#pragma unroll
    for (int kt = 0; kt < 4; ++kt) {
      const int ko = kt * 32 + quad * 8;
      bf16x8 aF[4], bF[4];
#pragma unroll
      for (int mt = 0; mt < 4; ++mt)
        aF[mt] = *(const bf16x8*)(fn + (size_t)(I0 + mt * 16 + l16) * DD + ko);
#pragma unroll
      for (int nt = 0; nt < 4; ++nt)
        bF[nt] = *(const bf16x8*)(fn + (size_t)(J0 + nt * 16 + l16) * DD + ko);
#pragma unroll
      for (int mt = 0; mt < 4; ++mt)
#pragma unroll
        for (int nt = 0; nt < 4; ++nt)
          acc[mt][nt] = __builtin_amdgcn_mfma_f32_16x16x32_bf16(
              bF[nt], aF[mt], acc[mt][nt], 0, 0, 0);  // SWAPPED operands
    }

    __syncthreads();  // previous subtile's phase 3 done reading sim

    // ---- Phase 2: exp -> LDS (bf16) ----
    const float tinv = 1.0f / 0.07f;
#pragma unroll
    for (int mt = 0; mt < 4; ++mt) {
      const int iLoc = wy * 64 + mt * 16 + l16;
#pragma unroll
      for (int nt = 0; nt < 4; ++nt) {
        const int jLoc = wx * 64 + nt * 16 + quad * 4;
        ushort4 w;
        w.x = f2bf(__expf(acc[mt][nt][0] * tinv));
        w.y = f2bf(__expf(acc[mt][nt][1] * tinv));
        w.z = f2bf(__expf(acc[mt][nt][2] * tinv));
        w.w = f2bf(__expf(acc[mt][nt][3] * tinv));
        *(ushort4*)(sim + iLoc * PADW + jLoc) = w;
      }
    }

    // ---- prefetch masks for it=0,1 (acc regs are dead now: disjoint peaks)
    const int* pB = pmask + (size_t)(I0g + rGrp) * NN + J0g + cl * 8;
    const int* nB = nmask + (size_t)(I0g + rGrp) * NN + J0g + cl * 8;
    int4 pa[3], pb[3], na[3], nb[3];
    pa[0] = *(const int4*)(pB);             pb[0] = *(const int4*)(pB + 4);
    na[0] = *(const int4*)(nB);             nb[0] = *(const int4*)(nB + 4);
    pa[1] = *(const int4*)(pB + 16 * NN);   pb[1] = *(const int4*)(pB + 16 * NN + 4);
    na[1] = *(const int4*)(nB + 16 * NN);   nb[1] = *(const int4*)(nB + 16 * NN + 4);

    __syncthreads();  // sim visible

    // ---- Phase 3: masked accumulation, depth-2 pipelined mask stream ----
#pragma unroll
    for (int it = 0; it < 8; ++it) {
      const int s = it % 3;
      if (it < 6) {  // prefetch it+2
        const int t = (it + 2) % 3;
        const size_t off = (size_t)(it + 2) * 16 * NN;
        pa[t] = *(const int4*)(pB + off);   pb[t] = *(const int4*)(pB + off + 4);
        na[t] = *(const int4*)(nB + off);   nb[t] = *(const int4*)(nB + off + 4);
      }
      const int rLoc = it * 16 + rGrp;
      const int iG = I0g + rLoc;
      const int dj = iG - (J0g + cl * 8);  // diagonal hits element r == dj
      const bf16x8 ev = *(const bf16x8*)(sim + rLoc * PADW + cl * 8);
      int pm8[8], nm8[8];
      *(int4*)&pm8[0] = pa[s]; *(int4*)&pm8[4] = pb[s];
      *(int4*)&nm8[0] = na[s]; *(int4*)&nm8[4] = nb[s];
      float p = 0.f, q = 0.f, c = 0.f;
#pragma unroll
      for (int r = 0; r < 8; ++r) {
        int pm = pm8[r];
        int nm = nm8[r];
        if (r == dj) { pm = 0; nm = 0; }  // zero self-contrast
        const float e = __uint_as_float(((unsigned int)(unsigned short)ev[r]) << 16);
        p = fmaf(e, (float)pm, p);
        q = fmaf(e, (float)nm, q);
        c += (float)pm;
      }
      accP[it] += p; accN[it] += q; accC[it] += c;
    }
  }

  // ---- epilogue: one 16-lane reduce per row, plain stores (no atomics) ----
  const size_t panelOff = (size_t)blockIdx.x * NN;
#pragma unroll
  for (int it = 0; it < 8; ++it) {
    float p = accP[it], q = accN[it], c = accC[it];
#pragma unroll
    for (int m = 1; m < 16; m <<= 1) {
      p += __shfl_xor(p, m, 64);
      q += __shfl_xor(q, m, 64);
      c += __shfl_xor(c, m, 64);
    }
    const int iG = I0g + it * 16 + rGrp;
    if (cl == 0)      pP[panelOff + iG] = p;
    else if (cl == 1) nP[panelOff + iG] = q;
    else if (cl == 2) cP[panelOff + iG] = c;
  }
}

// ---------------------------------------------------------------------------
// Kernel 3a: reduce the PANELS partials per row, per-row loss term,
// block-level sum -> blkSum[32]. Coalesced, L2-resident (1.5 MB).
// ---------------------------------------------------------------------------
__global__ __launch_bounds__(256) void finalize1(
    const float* __restrict__ pP, const float* __restrict__ nP,
    const float* __restrict__ cP, float* __restrict__ blkSum) {
  const int r = blockIdx.x * 256 + threadIdx.x;
  float p = 0.f, q = 0.f, c = 0.f;
#pragma unroll
  for (int k = 0; k < PANELS; ++k) {
    p += pP[(size_t)k * NN + r];
    q += nP[(size_t)k * NN + r];
    c += cP[(size_t)k * NN + r];
  }
  float s = logf(p / (p + q)) / c;
#pragma unroll
  for (int m = 1; m < 64; m <<= 1) s += __shfl_xor(s, m, 64);
  __shared__ float ws4[4];
  if ((threadIdx.x & 63) == 0) ws4[threadIdx.x >> 6] = s;
  __syncthreads();
  if (threadIdx.x == 0)
    blkSum[blockIdx.x] = ws4[0] + ws4[1] + ws4[2] + ws4[3];
}

// Kernel 3b: final 32-value sum -> loss
__global__ void finalize2(const float* __restrict__ blkSum,
                          float* __restrict__ out) {
  float s = (threadIdx.x < NN / 256) ? blkSum[threadIdx.x] : 0.f;
#pragma unroll
  for (int m = 1; m < 64; m <<= 1) s += __shfl_xor(s, m, 64);
  if (threadIdx.x == 0) out[0] = -s / (float)NN;
}

extern "C" void kernel_launch(void* const* d_in, const int* in_sizes, int n_in,
                              void* d_out, int out_size, void* d_ws, size_t ws_size,
                              hipStream_t stream) {
  const float* features = (const float*)d_in[0];
  const int* pmask = (const int*)d_in[1];
  const int* nmask = (const int*)d_in[2];
  float* out = (float*)d_out;

  char* ws = (char*)d_ws;
  __hip_bfloat16* fn = (__hip_bfloat16*)ws;                       // 2 MB
  float* pP = (float*)(ws + (size_t)NN * DD * sizeof(__hip_bfloat16));
  float* nP = pP + (size_t)PANELS * NN;                           // 3x 512 KB
  float* cP = nP + (size_t)PANELS * NN;
  float* blkSum = cP + (size_t)PANELS * NN;                       // 128 B

  normalize_kernel<<<NN / 4, 256, 0, stream>>>(features, fn);
  ssnt_main<<<dim3(PANELS, NN / 128), 256, 0, stream>>>(fn, pmask, nmask,
                                                        pP, nP, cP);
  finalize1<<<NN / 256, 256, 0, stream>>>(pP, nP, cP, blkSum);
  finalize2<<<1, 64, 0, stream>>>(blkSum, out);
}

// Round 2
// 553.958 us; speedup vs baseline: 1.0657x; 1.0657x over previous
//
#include <hip/hip_runtime.h>
#include <hip/hip_bf16.h>
#include <stdint.h>
#include <stddef.h>

#define NN 8192
#define DD 128
#define PADW 136    // LDS row stride in bf16: 272 B, breaks phase-2/3 bank conflicts
#define PANELS 64   // one partial-sum panel per j-tile (grid.x)

typedef __attribute__((ext_vector_type(8))) short bf16x8;
typedef __attribute__((ext_vector_type(4))) float f32x4;

static __device__ __forceinline__ unsigned short f2bf(float x) {
  __hip_bfloat16 h = __float2bfloat16(x);
  return *(unsigned short*)&h;
}

// ---------------------------------------------------------------------------
// Kernel 1: row-normalize features (fp32) and cast to bf16. One wave per row.
// ---------------------------------------------------------------------------
__global__ __launch_bounds__(256) void normalize_kernel(
    const float* __restrict__ f, __hip_bfloat16* __restrict__ fn) {
  const int wave = threadIdx.x >> 6;
  const int lane = threadIdx.x & 63;
  const int row = blockIdx.x * 4 + wave;
  const float2 v = ((const float2*)(f + (size_t)row * DD))[lane];
  float ss = v.x * v.x + v.y * v.y;
#pragma unroll
  for (int m = 1; m < 64; m <<= 1) ss += __shfl_xor(ss, m, 64);
  const float inv = 1.0f / fmaxf(sqrtf(ss), 1e-8f);
  __hip_bfloat162 o;
  o.x = __float2bfloat16(v.x * inv);
  o.y = __float2bfloat16(v.y * inv);
  ((__hip_bfloat162*)(fn + (size_t)row * DD))[lane] = o;
}

// ---------------------------------------------------------------------------
// Phase 3 body: lane-local masked accumulation, NO per-iteration reduction.
// DIAG=true only for the 64 diagonal blocks (wave-uniform branch at call site)
// ---------------------------------------------------------------------------
template <bool DIAG>
static __device__ __forceinline__ void phase3_run(
    const __hip_bfloat16* __restrict__ simc,  // sim + cl*8
    const int* __restrict__ pB, const int* __restrict__ nB,
    int djBase, int rGrp,
    float* __restrict__ accP, float* __restrict__ accQ,
    int* __restrict__ accC) {
#pragma unroll
  for (int it = 0; it < 8; ++it) {
    const int rLoc = it * 16 + rGrp;
    const size_t off = (size_t)it * 16 * NN;
    const int4 pa = *(const int4*)(pB + off);
    const int4 pb = *(const int4*)(pB + off + 4);
    const int4 na = *(const int4*)(nB + off);
    const int4 nb = *(const int4*)(nB + off + 4);
    const bf16x8 ev = *(const bf16x8*)(simc + (size_t)rLoc * PADW);
    int pm8[8], nm8[8];
    *(int4*)&pm8[0] = pa; *(int4*)&pm8[4] = pb;
    *(int4*)&nm8[0] = na; *(int4*)&nm8[4] = nb;
    const int dj = DIAG ? (djBase + rLoc) : -1;
    float p = 0.f, q = 0.f;
    int c = 0;
#pragma unroll
    for (int r = 0; r < 8; ++r) {
      int pm = pm8[r];
      int nm = nm8[r];
      if (DIAG) {
        if (r == dj) { pm = 0; nm = 0; }  // zero self-contrast
      }
      const float e = __uint_as_float(((unsigned int)(unsigned short)ev[r]) << 16);
      p = fmaf(e, (float)pm, p);
      q = fmaf(e, (float)nm, q);
      c += pm;
    }
    accP[it] = p; accQ[it] = q; accC[it] = c;
  }
}

// ---------------------------------------------------------------------------
// Kernel 2: one 128x128 sim tile per block.
//   Phase 1: bf16 MFMA GEMM, fragments straight from L2 (fn is 2 MB).
//   Phase 2: exp(sim/T) -> LDS bf16.
//   Phase 3: lane-local masked accumulation (deferred reduce -> 24 independent
//            butterfly chains in the epilogue instead of 8 serial ones).
//   Epilogue: ATOMIC ? 3 atomics/row : plain stores into per-j-panel partials.
// No register state crosses the GEMM phase -> no spills (round-1 lesson).
// ---------------------------------------------------------------------------
template <bool ATOMIC>
__global__ __launch_bounds__(256, 4) void ssnt_main(
    const __hip_bfloat16* __restrict__ fn,
    const int* __restrict__ pmask,
    const int* __restrict__ nmask,
    float* __restrict__ pP, float* __restrict__ nP, float* __restrict__ cP) {
  __shared__ __hip_bfloat16 sim[128 * PADW];  // 34 KB -> 4 blocks/CU

  const int tid = threadIdx.x;
  const int lane = tid & 63;
  const int quad = lane >> 4;
  const int l16 = lane & 15;
  const int wx = (tid >> 6) & 1;
  const int wy = tid >> 7;
  const int rGrp = tid >> 4;  // phase-3 row group
  const int cl = tid & 15;    // phase-3 col group (8 cols each)

  const int I0g = blockIdx.y * 128;
  const int J0g = blockIdx.x * 128;
  const int I0 = I0g + wy * 64;
  const int J0 = J0g + wx * 64;

  // ---- Phase 1: GEMM ----
  f32x4 acc[4][4] = {};
#pragma unroll
  for (int kt = 0; kt < 4; ++kt) {
    const int ko = kt * 32 + quad * 8;
    bf16x8 aF[4], bF[4];
#pragma unroll
    for (int mt = 0; mt < 4; ++mt)
      aF[mt] = *(const bf16x8*)(fn + (size_t)(I0 + mt * 16 + l16) * DD + ko);
#pragma unroll
    for (int nt = 0; nt < 4; ++nt)
      bF[nt] = *(const bf16x8*)(fn + (size_t)(J0 + nt * 16 + l16) * DD + ko);
#pragma unroll
    for (int mt = 0; mt < 4; ++mt)
#pragma unroll
      for (int nt = 0; nt < 4; ++nt)
        acc[mt][nt] = __builtin_amdgcn_mfma_f32_16x16x32_bf16(
            bF[nt], aF[mt], acc[mt][nt], 0, 0, 0);  // SWAPPED operands
  }

  // ---- Phase 2: exp -> LDS (bf16) ----
  const float tinv = 1.0f / 0.07f;
#pragma unroll
  for (int mt = 0; mt < 4; ++mt) {
    const int iLoc = wy * 64 + mt * 16 + l16;
#pragma unroll
    for (int nt = 0; nt < 4; ++nt) {
      const int jLoc = wx * 64 + nt * 16 + quad * 4;
      ushort4 w;
      w.x = f2bf(__expf(acc[mt][nt][0] * tinv));
      w.y = f2bf(__expf(acc[mt][nt][1] * tinv));
      w.z = f2bf(__expf(acc[mt][nt][2] * tinv));
      w.w = f2bf(__expf(acc[mt][nt][3] * tinv));
      *(ushort4*)(sim + iLoc * PADW + jLoc) = w;
    }
  }
  __syncthreads();

  // ---- Phase 3: lane-local accumulation (acc regs are dead now) ----
  const int* pB = pmask + (size_t)(I0g + rGrp) * NN + J0g + cl * 8;
  const int* nB = nmask + (size_t)(I0g + rGrp) * NN + J0g + cl * 8;
  float accP[8], accQ[8];
  int accC[8];
  if (I0g == J0g)
    phase3_run<true>(sim + cl * 8, pB, nB, I0g - J0g - cl * 8, rGrp,
                     accP, accQ, accC);
  else
    phase3_run<false>(sim + cl * 8, pB, nB, 0, rGrp, accP, accQ, accC);

  // ---- Epilogue: batched butterfly (24 independent chains), then output ----
#pragma unroll
  for (int m = 1; m < 16; m <<= 1) {
#pragma unroll
    for (int it = 0; it < 8; ++it) {
      accP[it] += __shfl_xor(accP[it], m, 64);
      accQ[it] += __shfl_xor(accQ[it], m, 64);
      accC[it] += __shfl_xor(accC[it], m, 64);
    }
  }
#pragma unroll
  for (int it = 0; it < 8; ++it) {
    const int iG = I0g + it * 16 + rGrp;
    if (ATOMIC) {
      if (cl == 0)      atomicAdd(&pP[iG], accP[it]);
      else if (cl == 1) atomicAdd(&nP[iG], accQ[it]);
      else if (cl == 2) atomicAdd(&cP[iG], (float)accC[it]);
    } else {
      const size_t panelOff = (size_t)blockIdx.x * NN;
      if (cl == 0)      pP[panelOff + iG] = accP[it];
      else if (cl == 1) nP[panelOff + iG] = accQ[it];
      else if (cl == 2) cP[panelOff + iG] = (float)accC[it];
    }
  }
}

// ---------------------------------------------------------------------------
// Kernel 3a: reduce panels per row, per-row loss term, block sum -> blkSum[32]
// ---------------------------------------------------------------------------
__global__ __launch_bounds__(256) void finalize1(
    const float* __restrict__ pP, const float* __restrict__ nP,
    const float* __restrict__ cP, int panels, float* __restrict__ blkSum) {
  const int r = blockIdx.x * 256 + threadIdx.x;
  float p = 0.f, q = 0.f, c = 0.f;
  for (int k = 0; k < panels; ++k) {
    p += pP[(size_t)k * NN + r];
    q += nP[(size_t)k * NN + r];
    c += cP[(size_t)k * NN + r];
  }
  float s = logf(p / (p + q)) / c;
#pragma unroll
  for (int m = 1; m < 64; m <<= 1) s += __shfl_xor(s, m, 64);
  __shared__ float ws4[4];
  if ((threadIdx.x & 63) == 0) ws4[threadIdx.x >> 6] = s;
  __syncthreads();
  if (threadIdx.x == 0)
    blkSum[blockIdx.x] = ws4[0] + ws4[1] + ws4[2] + ws4[3];
}

// Kernel 3b: final 32-value sum -> loss
__global__ void finalize2(const float* __restrict__ blkSum,
                          float* __restrict__ out) {
  float s = (threadIdx.x < NN / 256) ? blkSum[threadIdx.x] : 0.f;
#pragma unroll
  for (int m = 1; m < 64; m <<= 1) s += __shfl_xor(s, m, 64);
  if (threadIdx.x == 0) out[0] = -s / (float)NN;
}

extern "C" void kernel_launch(void* const* d_in, const int* in_sizes, int n_in,
                              void* d_out, int out_size, void* d_ws, size_t ws_size,
                              hipStream_t stream) {
  const float* features = (const float*)d_in[0];
  const int* pmask = (const int*)d_in[1];
  const int* nmask = (const int*)d_in[2];
  float* out = (float*)d_out;

  char* ws = (char*)d_ws;
  __hip_bfloat16* fn = (__hip_bfloat16*)ws;  // 2 MB
  float* base = (float*)(ws + (size_t)NN * DD * sizeof(__hip_bfloat16));

  normalize_kernel<<<NN / 4, 256, 0, stream>>>(features, fn);

  const size_t needPanels =
      (size_t)NN * DD * 2 + 3ull * PANELS * NN * sizeof(float) + 256;
  if (ws_size >= needPanels) {
    // panel path: atomic-free, no memset
    float* pP = base;
    float* nP = pP + (size_t)PANELS * NN;
    float* cP = nP + (size_t)PANELS * NN;
    float* blkSum = cP + (size_t)PANELS * NN;
    ssnt_main<false><<<dim3(NN / 128, NN / 128), 256, 0, stream>>>(
        fn, pmask, nmask, pP, nP, cP);
    finalize1<<<NN / 256, 256, 0, stream>>>(pP, nP, cP, PANELS, blkSum);
    finalize2<<<1, 64, 0, stream>>>(blkSum, out);
  } else {
    // fallback: atomic accumulation into [NN] arrays
    float* pP = base;
    float* nP = pP + NN;
    float* cP = nP + NN;
    float* blkSum = cP + NN;
    hipMemsetAsync(pP, 0, 3 * (size_t)NN * sizeof(float), stream);
    ssnt_main<true><<<dim3(NN / 128, NN / 128), 256, 0, stream>>>(
        fn, pmask, nmask, pP, nP, cP);
    finalize1<<<NN / 256, 256, 0, stream>>>(pP, nP, cP, 1, blkSum);
    finalize2<<<1, 64, 0, stream>>>(blkSum, out);
  }
}